// Round 6
// baseline (188.175 us; speedup 1.0000x reference)
//
#include <hip/hip_runtime.h>
#include <math.h>

// Problem constants (B=8, T=4096, D=256, K=1024)
#define NTOK   32768
#define NDIM   256
#define NCODE  1024
#define CHUNK  4096           // f16 per (strip,kc8) chunk: 128 codes x 32 dims = 8 KB

typedef _Float16 f16x8 __attribute__((ext_vector_type(8)));
typedef float    f32x4 __attribute__((ext_vector_type(4)));

// ---------------------------------------------------------------------------
// Prep: split codebook (fp32) into f16 hi/lo planes, blocked k-major layout.
//   chunk = (strip = row/128, kc8 = dim/32); within chunk:
//   off_f16 = (r>>4)*512 + (g&3)*128 + (r&15)*8     (r = row%128, g&3 = k-quad)
// One MFMA B-fragment (16 codes x 8 dims) is a contiguous 1 KB region ->
// a wave's 16B/lane global load of it is perfectly coalesced.
// Plus exact fp32 row norms. ~1 MB total (L2-resident everywhere).
// ---------------------------------------------------------------------------
__global__ __launch_bounds__(256) void prep_cb(
        const float* __restrict__ cb,
        _Float16* __restrict__ ch, _Float16* __restrict__ cl,
        float* __restrict__ csq) {
    const int L   = blockIdx.x * 256 + threadIdx.x;   // 0..32767
    const int row = L >> 5;                           // code 0..1023
    const int g   = L & 31;                           // 8-elem group in 256 dims

    const float* src = cb + (size_t)row * NDIM + g * 8;
    float4 a0 = *(const float4*)src;
    float4 a1 = *(const float4*)(src + 4);
    float v[8] = {a0.x, a0.y, a0.z, a0.w, a1.x, a1.y, a1.z, a1.w};
    f16x8 hi, lo;
    float s = 0.f;
    #pragma unroll
    for (int e = 0; e < 8; ++e) {
        _Float16 h = (_Float16)v[e];
        hi[e] = h;
        lo[e] = (_Float16)(v[e] - (float)h);
        s += v[e] * v[e];
    }
    const int r = row & 127;
    const size_t dst = (size_t)((row >> 7) * 8 + (g >> 2)) * CHUNK
                     + (r >> 4) * 512 + (g & 3) * 128 + (r & 15) * 8;
    *(f16x8*)&ch[dst] = hi;
    *(f16x8*)&cl[dst] = lo;
    #pragma unroll
    for (int off = 16; off > 0; off >>= 1) s += __shfl_down(s, off, 32);
    if ((threadIdx.x & 31) == 0) csq[row] = s;
}

// ---------------------------------------------------------------------------
// Main: A-stationary fused VQ at 4 WAVES/SIMD (the round-0..5 invariant:
// five different staging schemes all tied at ~65us / 31% MfmaUtil because
// ~208 combined regs/wave capped occupancy at 2 waves/SIMD -- neither the
// MFMA pipe (24.8us floor) nor the TA pipe (27us floor) could interleave).
// Fix: halve per-wave state. 16-wave 1024-thread block, 64 tokens:
//   wave = (my in 2) x (nx in 4) x (kh in 2)
//   - 32 token rows (mt in 2), but only 2 column-tiles (32 codes) and only
//     HALF the K dims (kh-half: kc8 = kh*4+c, c in 0..3).
//   - regs: ah/al 64 + acc 16 + frags 16 + bv/bi 16 + misc ~14 = ~126 <= 128.
//     The 1024-thr block forces the compiler contract (16 waves @ 4/SIMD).
// kh-partners sum partial dots once per strip via a strip-parity
// double-buffered 64 KB LDS region (8 __syncthreads total, no per-chunk
// lockstep); kh0 waves own csq/argmin/epilogue. B-frags global->reg direct
// (round-5 structure); all waitcnts compiler-managed.
// 3-pass f16 MFMA (ah.bh + al.bh + ah.bl); acc zeroed via zero-C at c==0.
// Layouts (verified): A/B frag [row=lane&15][k=(lane>>4)*8+j]; D col=lane&15,
// row=(lane>>4)*4+reg.
// ---------------------------------------------------------------------------
__global__ __launch_bounds__(1024) void vq_main(
        const float* __restrict__ z,
        const _Float16* __restrict__ ch, const _Float16* __restrict__ cl,
        const float* __restrict__ csq, const float* __restrict__ cb,
        float* __restrict__ zq, float* __restrict__ io) {
    // strip-parity double-buffered acc-merge: [par][my*4+nx][lane][16 f32]
    __shared__ float mbuf[2][8][64][16];   // 64 KB

    const int tid  = threadIdx.x;
    const int w    = tid >> 6;                 // 0..15
    const int lane = tid & 63;
    const int quad = lane >> 4, lr = lane & 15;
    const int kh   = w >> 3;                   // 0..1  K-half
    const int my   = (w >> 2) & 1;             // 0..1  token half
    const int nx   = w & 3;                    // 0..3  column quarter
    const int w4   = (my << 2) | nx;           // merge slot 0..7
    const int m0   = blockIdx.x * 64;

    // ---- A frags for my rows, my K-half: A[m=my*32+mt*16+lr][k=(kh*4+c)*32+quad*8+j]
    f16x8 ah[2][4], al[2][4];
    #pragma unroll
    for (int mt = 0; mt < 2; ++mt) {
        const float* zp = z + (size_t)(m0 + my * 32 + mt * 16 + lr) * NDIM
                        + kh * 128 + quad * 8;
        #pragma unroll
        for (int c = 0; c < 4; ++c) {
            float4 a0 = *(const float4*)(zp + c * 32);
            float4 a1 = *(const float4*)(zp + c * 32 + 4);
            float v[8] = {a0.x, a0.y, a0.z, a0.w, a1.x, a1.y, a1.z, a1.w};
            #pragma unroll
            for (int e = 0; e < 8; ++e) {
                _Float16 h = (_Float16)v[e];
                ah[mt][c][e] = h;
                al[mt][c][e] = (_Float16)(v[e] - (float)h);
            }
        }
    }

    // B frag byte offsets for my 2 column-tiles (t=0,1): contiguous 1 KB each
    const int boff0 = (nx * 2) * 512 + quad * 128 + lr * 8;
    const int boff1 = boff0 + 512;

    float bv[2][4];
    int   bi[2][4];
    #pragma unroll
    for (int mt = 0; mt < 2; ++mt)
        #pragma unroll
        for (int r = 0; r < 4; ++r) { bv[mt][r] = INFINITY; bi[mt][r] = 0x7fffffff; }

    const f32x4 zz = (f32x4){0.f, 0.f, 0.f, 0.f};
    f32x4 acc[2][2];

    for (int s = 0; s < 8; ++s) {
        // ---- my 4 chunks of this strip (kc8 = kh*4 + c) ----
        const size_t cbase = (size_t)(s * 8 + kh * 4) * CHUNK;
        #pragma unroll
        for (int c = 0; c < 4; ++c) {
            const _Float16* ph = ch + cbase + (size_t)c * CHUNK;
            const _Float16* pl = cl + cbase + (size_t)c * CHUNK;
            f16x8 bh0 = *(const f16x8*)&ph[boff0];
            f16x8 bh1 = *(const f16x8*)&ph[boff1];
            f16x8 bl0 = *(const f16x8*)&pl[boff0];
            f16x8 bl1 = *(const f16x8*)&pl[boff1];
            __builtin_amdgcn_s_setprio(1);
            #pragma unroll
            for (int mt = 0; mt < 2; ++mt) {
                acc[mt][0] = __builtin_amdgcn_mfma_f32_16x16x32_f16(
                    ah[mt][c], bh0, (c == 0) ? zz : acc[mt][0], 0, 0, 0);
                acc[mt][0] = __builtin_amdgcn_mfma_f32_16x16x32_f16(
                    al[mt][c], bh0, acc[mt][0], 0, 0, 0);
                acc[mt][0] = __builtin_amdgcn_mfma_f32_16x16x32_f16(
                    ah[mt][c], bl0, acc[mt][0], 0, 0, 0);
                acc[mt][1] = __builtin_amdgcn_mfma_f32_16x16x32_f16(
                    ah[mt][c], bh1, (c == 0) ? zz : acc[mt][1], 0, 0, 0);
                acc[mt][1] = __builtin_amdgcn_mfma_f32_16x16x32_f16(
                    al[mt][c], bh1, acc[mt][1], 0, 0, 0);
                acc[mt][1] = __builtin_amdgcn_mfma_f32_16x16x32_f16(
                    ah[mt][c], bl1, acc[mt][1], 0, 0, 0);
            }
            __builtin_amdgcn_s_setprio(0);
        }

        // ---- kh-merge: kh1 publishes partials, kh0 sums + folds argmin ----
        const int par = s & 1;
        if (kh) {
            float* mp = &mbuf[par][w4][lane][0];
            *(f32x4*)(mp +  0) = acc[0][0];
            *(f32x4*)(mp +  4) = acc[0][1];
            *(f32x4*)(mp +  8) = acc[1][0];
            *(f32x4*)(mp + 12) = acc[1][1];
        }
        __syncthreads();
        if (!kh) {
            float cs0 = csq[s * 128 + (nx * 2) * 16 + lr];
            float cs1 = csq[s * 128 + (nx * 2 + 1) * 16 + lr];
            const float* mp = &mbuf[par][w4][lane][0];
            f32x4 p00 = *(const f32x4*)(mp +  0);
            f32x4 p01 = *(const f32x4*)(mp +  4);
            f32x4 p10 = *(const f32x4*)(mp +  8);
            f32x4 p11 = *(const f32x4*)(mp + 12);
            #pragma unroll
            for (int mt = 0; mt < 2; ++mt) {
                f32x4 d0 = (mt == 0) ? p00 : p10;
                f32x4 d1 = (mt == 0) ? p01 : p11;
                #pragma unroll
                for (int r = 0; r < 4; ++r) {
                    float v0 = cs0 - 2.0f * (acc[mt][0][r] + d0[r]);
                    int   n0 = s * 128 + (nx * 2) * 16 + lr;
                    if (v0 < bv[mt][r] || (v0 == bv[mt][r] && n0 < bi[mt][r])) {
                        bv[mt][r] = v0; bi[mt][r] = n0;
                    }
                    float v1 = cs1 - 2.0f * (acc[mt][1][r] + d1[r]);
                    int   n1 = s * 128 + (nx * 2 + 1) * 16 + lr;
                    if (v1 < bv[mt][r] || (v1 == bv[mt][r] && n1 < bi[mt][r])) {
                        bv[mt][r] = v1; bi[mt][r] = n1;
                    }
                }
            }
        }
    }

    // ---- butterfly over the 16 lanes sharing each row (kh0 waves) ----
    if (!kh) {
        #pragma unroll
        for (int msk = 1; msk < 16; msk <<= 1)
            #pragma unroll
            for (int mt = 0; mt < 2; ++mt)
                #pragma unroll
                for (int r = 0; r < 4; ++r) {
                    float ov = __shfl_xor(bv[mt][r], msk, 64);
                    int   oi = __shfl_xor(bi[mt][r], msk, 64);
                    if (ov < bv[mt][r] || (ov == bv[mt][r] && oi < bi[mt][r])) {
                        bv[mt][r] = ov; bi[mt][r] = oi;
                    }
                }
    }

    // ---- cross-nx merge + index write + zq gather (reuse mbuf[0] slot 0) ----
    float* sval  = &mbuf[0][0][0][0];        // [64][4]
    int*   sidx  = (int*)(sval + 256);       // [64][4]
    int*   bestS = (int*)(sval + 512);       // [64]

    if (!kh && lr == 0) {
        #pragma unroll
        for (int mt = 0; mt < 2; ++mt)
            #pragma unroll
            for (int r = 0; r < 4; ++r) {
                int row = my * 32 + mt * 16 + quad * 4 + r;   // 0..63
                sval[row * 4 + nx] = bv[mt][r];
                sidx[row * 4 + nx] = bi[mt][r];
            }
    }
    __syncthreads();

    if (tid < 64) {
        float bvv = sval[tid * 4];
        int   bii = sidx[tid * 4];
        #pragma unroll
        for (int k = 1; k < 4; ++k) {
            float v = sval[tid * 4 + k];
            int   i = sidx[tid * 4 + k];
            if (v < bvv || (v == bvv && i < bii)) { bvv = v; bii = i; }
        }
        bestS[tid] = bii;
        io[m0 + tid] = (float)bii;
    }
    __syncthreads();

    // ---- gather z_q: 64 rows x 1 KB from cb (L2-hot), coalesced float4 ----
    const int tr = tid >> 4, tc = tid & 15;   // 64 rows x 16 threads
    const float* src = cb + (size_t)bestS[tr] * NDIM;
    float*       dst = zq + (size_t)(m0 + tr) * NDIM;
    #pragma unroll
    for (int q = 0; q < 4; ++q) {
        int col = q * 64 + tc * 4;
        *(float4*)&dst[col] = *(const float4*)&src[col];
    }
}

// ---------------------------------------------------------------------------
extern "C" void kernel_launch(void* const* d_in, const int* in_sizes, int n_in,
                              void* d_out, int out_size, void* d_ws, size_t ws_size,
                              hipStream_t stream) {
    const float* z  = (const float*)d_in[0];
    const float* cb = (const float*)d_in[1];

    float* zq = (float*)d_out;                        // 32768*256 floats
    float* io = (float*)d_out + (size_t)NTOK * NDIM;  // 32768 floats (indices)

    _Float16* ch  = (_Float16*)d_ws;                  // 0.5 MB
    _Float16* cl  = ch + (size_t)NCODE * NDIM;        // 0.5 MB
    float*    csq = (float*)(cl + (size_t)NCODE * NDIM);  // 4 KB

    prep_cb<<<NCODE * 32 / 256, 256, 0, stream>>>(cb, ch, cl, csq);

    vq_main<<<NTOK / 64, 1024, 0, stream>>>(z, ch, cl, csq, cb, zq, io);
}

// Round 7
// 155.755 us; speedup vs baseline: 1.2081x; 1.2081x over previous
//
#include <hip/hip_runtime.h>
#include <math.h>

// Problem constants (B=8, T=4096, D=256, K=1024)
#define NTOK   32768
#define NDIM   256
#define NCODE  1024
#define CHUNK  4096           // f16 per (strip,kc8) chunk: 128 codes x 32 dims = 8 KB

typedef _Float16 f16x8 __attribute__((ext_vector_type(8)));
typedef float    f32x4 __attribute__((ext_vector_type(4)));

// ---------------------------------------------------------------------------
// Prep: split codebook (fp32) into f16 hi/lo planes, blocked k-major layout.
//   chunk = (strip = row/128, kc8 = dim/32); within chunk:
//   off_f16 = (r>>4)*512 + (g&3)*128 + (r&15)*8     (r = row%128, g&3 = k-quad)
// One MFMA B-fragment (16 codes x 8 dims... full 16x32 tile) is a contiguous
// 1 KB region -> a wave's 16B/lane global load of it is perfectly coalesced.
// Plus exact fp32 row norms. ~1 MB total (L2-resident everywhere).
// ---------------------------------------------------------------------------
__global__ __launch_bounds__(256) void prep_cb(
        const float* __restrict__ cb,
        _Float16* __restrict__ ch, _Float16* __restrict__ cl,
        float* __restrict__ csq) {
    const int L   = blockIdx.x * 256 + threadIdx.x;   // 0..32767
    const int row = L >> 5;                           // code 0..1023
    const int g   = L & 31;                           // 8-elem group in 256 dims

    const float* src = cb + (size_t)row * NDIM + g * 8;
    float4 a0 = *(const float4*)src;
    float4 a1 = *(const float4*)(src + 4);
    float v[8] = {a0.x, a0.y, a0.z, a0.w, a1.x, a1.y, a1.z, a1.w};
    f16x8 hi, lo;
    float s = 0.f;
    #pragma unroll
    for (int e = 0; e < 8; ++e) {
        _Float16 h = (_Float16)v[e];
        hi[e] = h;
        lo[e] = (_Float16)(v[e] - (float)h);
        s += v[e] * v[e];
    }
    const int r = row & 127;
    const size_t dst = (size_t)((row >> 7) * 8 + (g >> 2)) * CHUNK
                     + (r >> 4) * 512 + (g & 3) * 128 + (r & 15) * 8;
    *(f16x8*)&ch[dst] = hi;
    *(f16x8*)&cl[dst] = lo;
    #pragma unroll
    for (int off = 16; off > 0; off >>= 1) s += __shfl_down(s, off, 32);
    if ((threadIdx.x & 31) == 0) csq[row] = s;
}

// ---------------------------------------------------------------------------
// Main: A-stationary fused VQ at 4 WAVES/SIMD with a 128-fitting wave plan.
// Campaign model (rounds 0-6): five 2-waves/SIMD structures all tie at
// ~65us / 31% MfmaUtil = MFMA floor (26us) + per-wave load-latency that two
// streams/SIMD cannot cover. Round 6 proved occupancy doubles when the
// register plan shrinks -- but an unpinned allocator chose a 64-VGPR budget
// and spilled ~25MB. This round:
//   wave = 16 token rows (mt=1) x 4 column-tiles (nx half), FULL K.
//   regs: ah/al 64 + acc 16 + frags <=32 + bv/bi 8 + misc ~15 ~= 118 <= 128.
//   block = 512 thr = 4 row-groups x 2 nx, 64 tokens; grid 512 -> 2
//   blocks/CU = 16 waves/CU = 4/SIMD, PINNED via amdgpu_waves_per_eu(4,4).
// B path = round-5's proven no-barrier global->reg direct reads from the
// L2-resident planes (no LDS in main loop, no barriers, no bank conflicts);
// latency hiding via TLP (4 streams/SIMD), per-wave ILP deliberately
// shallow (load tile-pair -> MFMA tile-pair).
// 3-pass f16 MFMA (ah.bh + al.bh + ah.bl); per-lane running argmin.
// Layouts (verified): A/B frag [row=lane&15][k=(lane>>4)*8+j]; D col=lane&15,
// row=(lane>>4)*4+reg.
// ---------------------------------------------------------------------------
__global__ __launch_bounds__(512)
__attribute__((amdgpu_waves_per_eu(4, 4)))
void vq_main(
        const float* __restrict__ z,
        const _Float16* __restrict__ ch, const _Float16* __restrict__ cl,
        const float* __restrict__ csq, const float* __restrict__ cb,
        float* __restrict__ zq, float* __restrict__ io) {
    __shared__ float sval[128];   // epilogue scratch only
    __shared__ int   sidx[128];
    __shared__ int   bestS[64];

    const int tid  = threadIdx.x;
    const int w    = tid >> 6;                 // 0..7
    const int lane = tid & 63;
    const int quad = lane >> 4, lr = lane & 15;
    const int rg   = w >> 1;                   // row-group 0..3 (16 rows each)
    const int nx   = w & 1;                    // column half
    const int m0   = blockIdx.x * 64;

    // ---- A frags: 16 rows, full K. A[m=rg*16+lr][k=c*32+quad*8+j] ----
    f16x8 ah[8], al[8];
    {
        const float* zp = z + (size_t)(m0 + rg * 16 + lr) * NDIM + quad * 8;
        #pragma unroll
        for (int c = 0; c < 8; ++c) {
            float4 a0 = *(const float4*)(zp + c * 32);
            float4 a1 = *(const float4*)(zp + c * 32 + 4);
            float v[8] = {a0.x, a0.y, a0.z, a0.w, a1.x, a1.y, a1.z, a1.w};
            #pragma unroll
            for (int e = 0; e < 8; ++e) {
                _Float16 h = (_Float16)v[e];
                ah[c][e] = h;
                al[c][e] = (_Float16)(v[e] - (float)h);
            }
        }
    }

    // B frag base: frag(chunk g, tile t) at pb? + g*4096 + t*512 (t folded
    // with nx: tiles nx*4 .. nx*4+3)
    const _Float16* pbh = ch + nx * 2048 + quad * 128 + lr * 8;
    const _Float16* pbl = cl + nx * 2048 + quad * 128 + lr * 8;

    float bv[4];
    int   bi[4];
    #pragma unroll
    for (int r = 0; r < 4; ++r) { bv[r] = INFINITY; bi[r] = 0x7fffffff; }

    const f32x4 zz = (f32x4){0.f, 0.f, 0.f, 0.f};

    for (int s = 0; s < 8; ++s) {
        f32x4 acc0 = zz, acc1 = zz, acc2 = zz, acc3 = zz;

        #pragma unroll
        for (int c = 0; c < 8; ++c) {          // kc8 within strip (static: ah[c])
            const _Float16* ph = pbh + (size_t)(s * 8 + c) * CHUNK;
            const _Float16* pl = pbl + (size_t)(s * 8 + c) * CHUNK;
            // tile pair 0/1
            f16x8 bh0 = *(const f16x8*)&ph[0];
            f16x8 bh1 = *(const f16x8*)&ph[512];
            f16x8 bl0 = *(const f16x8*)&pl[0];
            f16x8 bl1 = *(const f16x8*)&pl[512];
            __builtin_amdgcn_s_setprio(1);
            acc0 = __builtin_amdgcn_mfma_f32_16x16x32_f16(ah[c], bh0, acc0, 0, 0, 0);
            acc0 = __builtin_amdgcn_mfma_f32_16x16x32_f16(al[c], bh0, acc0, 0, 0, 0);
            acc0 = __builtin_amdgcn_mfma_f32_16x16x32_f16(ah[c], bl0, acc0, 0, 0, 0);
            acc1 = __builtin_amdgcn_mfma_f32_16x16x32_f16(ah[c], bh1, acc1, 0, 0, 0);
            acc1 = __builtin_amdgcn_mfma_f32_16x16x32_f16(al[c], bh1, acc1, 0, 0, 0);
            acc1 = __builtin_amdgcn_mfma_f32_16x16x32_f16(ah[c], bl1, acc1, 0, 0, 0);
            __builtin_amdgcn_s_setprio(0);
            // tile pair 2/3
            f16x8 bh2 = *(const f16x8*)&ph[1024];
            f16x8 bh3 = *(const f16x8*)&ph[1536];
            f16x8 bl2 = *(const f16x8*)&pl[1024];
            f16x8 bl3 = *(const f16x8*)&pl[1536];
            __builtin_amdgcn_s_setprio(1);
            acc2 = __builtin_amdgcn_mfma_f32_16x16x32_f16(ah[c], bh2, acc2, 0, 0, 0);
            acc2 = __builtin_amdgcn_mfma_f32_16x16x32_f16(al[c], bh2, acc2, 0, 0, 0);
            acc2 = __builtin_amdgcn_mfma_f32_16x16x32_f16(ah[c], bl2, acc2, 0, 0, 0);
            acc3 = __builtin_amdgcn_mfma_f32_16x16x32_f16(ah[c], bh3, acc3, 0, 0, 0);
            acc3 = __builtin_amdgcn_mfma_f32_16x16x32_f16(al[c], bh3, acc3, 0, 0, 0);
            acc3 = __builtin_amdgcn_mfma_f32_16x16x32_f16(ah[c], bl3, acc3, 0, 0, 0);
            __builtin_amdgcn_s_setprio(0);
        }

        // ---- fold strip s into the running per-lane argmin ----
        #define FOLD1(ACC, T) do {                                           \
            const int   _n  = s * 128 + (nx * 4 + (T)) * 16 + lr;            \
            const float _cs = csq[_n];                                       \
            _Pragma("unroll")                                                \
            for (int _r = 0; _r < 4; ++_r) {                                 \
                float _v = _cs - 2.0f * ACC[_r];                             \
                if (_v < bv[_r] || (_v == bv[_r] && _n < bi[_r])) {          \
                    bv[_r] = _v; bi[_r] = _n;                                \
                }                                                            \
            }                                                                \
        } while (0)
        FOLD1(acc0, 0);
        FOLD1(acc1, 1);
        FOLD1(acc2, 2);
        FOLD1(acc3, 3);
        #undef FOLD1
    }

    // ---- butterfly over the 16 lanes sharing each row ----
    #pragma unroll
    for (int msk = 1; msk < 16; msk <<= 1)
        #pragma unroll
        for (int r = 0; r < 4; ++r) {
            float ov = __shfl_xor(bv[r], msk, 64);
            int   oi = __shfl_xor(bi[r], msk, 64);
            if (ov < bv[r] || (ov == bv[r] && oi < bi[r])) {
                bv[r] = ov; bi[r] = oi;
            }
        }

    // ---- cross-nx merge + index write + zq gather ----
    if (lr == 0) {
        #pragma unroll
        for (int r = 0; r < 4; ++r) {
            int row = rg * 16 + quad * 4 + r;   // 0..63
            sval[row * 2 + nx] = bv[r];
            sidx[row * 2 + nx] = bi[r];
        }
    }
    __syncthreads();

    if (tid < 64) {
        float v0 = sval[tid * 2], v1 = sval[tid * 2 + 1];
        int   i0 = sidx[tid * 2], i1 = sidx[tid * 2 + 1];
        bool take1 = (v1 < v0) || (v1 == v0 && i1 < i0);
        int best = take1 ? i1 : i0;
        bestS[tid] = best;
        io[m0 + tid] = (float)best;
    }
    __syncthreads();

    // ---- gather z_q: 64 rows x 1 KB from cb (L2-hot), coalesced float4 ----
    const int gr = tid >> 3, gc = tid & 7;     // 64 rows x 8 threads
    const float* src = cb + (size_t)bestS[gr] * NDIM;
    float*       dst = zq + (size_t)(m0 + gr) * NDIM;
    #pragma unroll
    for (int q = 0; q < 8; ++q) {
        int col = q * 32 + gc * 4;
        *(float4*)&dst[col] = *(const float4*)&src[col];
    }
}

// ---------------------------------------------------------------------------
extern "C" void kernel_launch(void* const* d_in, const int* in_sizes, int n_in,
                              void* d_out, int out_size, void* d_ws, size_t ws_size,
                              hipStream_t stream) {
    const float* z  = (const float*)d_in[0];
    const float* cb = (const float*)d_in[1];

    float* zq = (float*)d_out;                        // 32768*256 floats
    float* io = (float*)d_out + (size_t)NTOK * NDIM;  // 32768 floats (indices)

    _Float16* ch  = (_Float16*)d_ws;                  // 0.5 MB
    _Float16* cl  = ch + (size_t)NCODE * NDIM;        // 0.5 MB
    float*    csq = (float*)(cl + (size_t)NCODE * NDIM);  // 4 KB

    prep_cb<<<NCODE * 32 / 256, 256, 0, stream>>>(cb, ch, cl, csq);

    vq_main<<<NTOK / 64, 512, 0, stream>>>(z, ch, cl, csq, cb, zq, io);
}